// Round 4
// baseline (519.752 us; speedup 1.0000x reference)
//
#include <hip/hip_runtime.h>
#include <stdint.h>

#define N 8192
#define G 7
#define T 512
#define NW 8          // waves per block
typedef uint32_t u32;
typedef uint16_t u16;

// Map float bits -> uint32 such that ascending uint order == DESCENDING float
// order, XLA total-order semantics. Stable LSD radix handles index tie-break.
__device__ __forceinline__ u32 enc_desc(float x) {
    u32 u = __float_as_uint(x);
    return (u & 0x80000000u) ? u : (~u & 0x7FFFFFFFu);
}
__device__ __forceinline__ float dec_desc(u32 k) {
    u32 u = (k & 0x80000000u) ? k : (~k & 0x7FFFFFFFu);
    return __uint_as_float(u);
}

// LDS budget: 32768(val) + 16384(idx) + 4096(wcnt) + 512(dsum) + 16(wsum)
// = 53776 B -> 54272 after 512B granularity; x3 = 162816 <= 163840 -> 3 blocks/CU.
__global__ __launch_bounds__(T, 6) void portfolio_radix_kernel(
    const float* __restrict__ x,
    float* __restrict__ bc,        // [B, N] float32
    float* __restrict__ idx_out)   // [B, N] indices as float32
{
    __shared__ u32 val_s[N];          // 32 KiB  sort keys (enc values)
    __shared__ u16 idx_s[N];          // 16 KiB  payload indices (<8192)
    __shared__ u16 wcnt[NW * 256];    // 4 KiB   per-wave digit counters (u16 halves)
    __shared__ u16 dsum[256];         // 512 B   global digit exclusive bases
    __shared__ u32 wsum[4];           // chunk totals for 256-wide scan

    const int t    = threadIdx.x;
    const int w    = t >> 6;          // wave 0..7
    const int lane = t & 63;
    const int row  = blockIdx.x;
    const float* xr  = x + (size_t)row * N;
    float* bcr = bc + (size_t)row * N;
    float* ixr = idx_out + (size_t)row * N;

    u32* wcnt32 = (u32*)wcnt;         // atomics/zeroing view (word = digit pair)

    // Element ownership e = 1024*w + 64*j + lane: ownership order (w, j, lane)
    // == index order, matching rank composition wave-base + program-order +
    // ascending-lane atomic serialization (tie-stability validated round 3).
    u32 hi[16];                        // sort key per element
    u32 lop[8];                        // packed u16 payload indices (VGPR diet)
    u32 rnk[8];                        // packed u16 in-wave ranks
#pragma unroll
    for (int j = 0; j < 16; ++j) {
        int e = (w << 10) | (j << 6) | lane;
        hi[j] = enc_desc(xr[e]);
        if ((j & 1) == 0) lop[j >> 1] = (u32)e;
        else              lop[j >> 1] |= ((u32)e) << 16;
        // bc is zero except head/tail G; store zeros now so the global-write
        // latency hides under the whole sort. Skip head/tail to avoid any
        // same-address write-order question with the epilogue softmax.
        if (e >= G && e < N - G) bcr[e] = 0.0f;
    }
    // zero own wave's counter row (128 words); phase A below touches only this
    // row from this wave -> no barrier needed before pass 0.
    wcnt32[(w << 7) + lane] = 0;
    wcnt32[(w << 7) + 64 + lane] = 0;

    for (int p = 0; p < 4; ++p) {
        const int shift = 8 * p;

        // ---- phase A: stable in-wave rank via ds_add_rtn_u32 on u16 halves.
        // Word (w*128 + d/2), half (d&1); counts <= 1024 so halves never carry.
        // Digit-pair (d, d^1) shares a word: same-word serialization stays in
        // ascending lane order per half -> per-digit stability preserved.
#pragma unroll
        for (int j = 0; j < 16; ++j) {
            u32 d   = (hi[j] >> shift) & 255u;
            u32 sh  = (d & 1u) << 4;
            u32 ret = atomicAdd(&wcnt32[(w << 7) + (d >> 1)], 1u << sh);
            u32 r   = (ret >> sh) & 0xFFFFu;
            if ((j & 1) == 0) rnk[j >> 1] = r;
            else              rnk[j >> 1] |= r << 16;
        }
        __syncthreads();                       // B1: all counts visible

        // ---- scan: threads 0..255 own one digit each (u16 element access;
        // neighbor digits share a word but ds_write_b16 uses byte enables).
        if (t < 256) {
            u32 run = 0;
#pragma unroll
            for (int ww = 0; ww < NW; ++ww) {  // serial over waves: exclusive
                u32 c = (u32)wcnt[(ww << 8) | t];
                wcnt[(ww << 8) | t] = (u16)run;
                run += c;
            }
            u32 v = run;                        // digit total; 64-wide scan
#pragma unroll
            for (int off = 1; off < 64; off <<= 1) {
                u32 u = __shfl_up(v, off, 64);
                if (lane >= off) v += u;
            }
            if (lane == 63) wsum[w] = v;        // chunk total (w = 0..3 here)
            dsum[t] = (u16)(v - run);           // exclusive within chunk
        }
        __syncthreads();                       // B2: dsum/wsum/bases visible

        // ---- fold own row + scatter + re-zero: single phase, wave-private.
        {
            u32 a0 = wsum[0], a1 = wsum[1], a2 = wsum[2];
#pragma unroll
            for (int i = 0; i < 4; ++i) {       // chunk index == i (compile-time)
                int d = lane + (i << 6);
                u32 addv = (i > 0 ? a0 : 0u) + (i > 1 ? a1 : 0u) + (i > 2 ? a2 : 0u);
                wcnt[(w << 8) + d] = (u16)((u32)wcnt[(w << 8) + d] + (u32)dsum[d] + addv);
            }
        }
#pragma unroll
        for (int j = 0; j < 16; ++j) {
            u32 d   = (hi[j] >> shift) & 255u;
            u32 sh  = ((u32)(j & 1)) << 4;
            u32 pos = ((rnk[j >> 1] >> sh) & 0xFFFFu) + (u32)wcnt[(w << 8) + d];
            u32 myi = (lop[j >> 1] >> sh) & 0xFFFFu;
            // last pass: only head/tail G values are ever read back
            if (p < 3 || pos < G || pos >= N - G) val_s[pos] = hi[j];
            idx_s[pos] = (u16)myi;
        }
        // compiler fence: u32 zero-stores must not hoist above the u16
        // base-reads in the scatter loop (mixed-width aliasing).
        asm volatile("" ::: "memory");
        wcnt32[(w << 7) + lane] = 0;
        wcnt32[(w << 7) + 64 + lane] = 0;
        __syncthreads();                       // B3: scatter + zero complete

        if (p < 3) {                           // gather; next phase A follows
            // with no barrier (disjoint arrays: val/idx vs wcnt)
#pragma unroll
            for (int j = 0; j < 16; ++j) {
                int e = (w << 10) | (j << 6) | lane;
                hi[j] = val_s[e];
                u32 ii = (u32)idx_s[e];
                if ((j & 1) == 0) lop[j >> 1] = ii;
                else              lop[j >> 1] |= ii << 16;
            }
        }
    }

    // ---- outputs: idx_s holds final descending order's original indices ----
#pragma unroll
    for (int j = 0; j < 16; ++j) {
        int e = (w << 10) | (j << 6) | lane;
        ixr[e] = (float)idx_s[e];
    }
    // winner: threads 0..6 redundantly compute softmax(top-7), write own slot
    if (t < G) {
        float s[G], ex[G], sum = 0.f;
#pragma unroll
        for (int g = 0; g < G; ++g) s[g] = dec_desc(val_s[g]);
        float m0 = s[0];                        // max (descending values)
#pragma unroll
        for (int g = 0; g < G; ++g) { ex[g] = expf(s[g] - m0); sum += ex[g]; }
        bcr[t] = ex[t] / sum;
    }
    // loser: threads 505..511 -> positions N-G..N-1.
    // -softmax(1 - bottom) == -softmax(-bottom) (shift invariance)
    if (t >= T - G) {
        float s[G], ex[G], sum = 0.f;
#pragma unroll
        for (int g = 0; g < G; ++g) s[g] = dec_desc(val_s[N - G + g]);
        float m0 = -s[G - 1];                   // max of -s (s descending)
#pragma unroll
        for (int g = 0; g < G; ++g) { ex[g] = expf(-s[g] - m0); sum += ex[g]; }
        bcr[(N - T) + t] = -ex[t - (T - G)] / sum;
    }
}

extern "C" void kernel_launch(void* const* d_in, const int* in_sizes, int n_in,
                              void* d_out, int out_size, void* d_ws, size_t ws_size,
                              hipStream_t stream) {
    const float* x = (const float*)d_in[0];
    float* out = (float*)d_out;
    const int B = in_sizes[0] / N;               // 4096
    float* bc  = out;                             // output 0: [B, N]
    float* idx = out + (size_t)B * N;             // output 1: [B, N] (as float32)
    portfolio_radix_kernel<<<B, T, 0, stream>>>(x, bc, idx);
}